// Round 3
// baseline (377.200 us; speedup 1.0000x reference)
//
#include <hip/hip_runtime.h>
#include <math.h>

// Problem constants (B,S,D,P,M from the reference)
#define BB 4
#define SS 8192
#define DD 512
#define PP 32
#define TT (PP + SS)            // 8224 tokens after concat
#define EPSV 1e-5f
#define NB 512                  // persistent grid: 2 blocks/CU guaranteed co-resident

// ws layout (floats):
//   [0]                 barrier counter (16B region, memset to 0 pre-launch)
//   part  [NB  * DD]    per-block column-sum partials of x      (1 MB)
//   vpart [128 * DD]    split-K partials of cbar @ Wv           (256 KB)
//   zpart [128 * DD]    split-K partials of y @ Wout            (256 KB)

#define LOAD_A(p)    __hip_atomic_load((p), __ATOMIC_RELAXED, __HIP_MEMORY_SCOPE_AGENT)
#define STORE_A(p,v) __hip_atomic_store((p), (v), __ATOMIC_RELAXED, __HIP_MEMORY_SCOPE_AGENT)

// Cumulative-counter grid barrier. All NB blocks co-resident (capacity math:
// launch_bounds(512,4) caps VGPR<=128 -> >=16 waves/CU -> >=2 blocks/CU ->
// 512 blocks resident on 256 CUs). Device-scope fences per G16.
__device__ __forceinline__ void gbar(unsigned* cnt, unsigned target) {
  __syncthreads();
  if (threadIdx.x == 0) {
    __threadfence();   // release prior ws writes (device scope)
    __hip_atomic_fetch_add(cnt, 1u, __ATOMIC_ACQ_REL, __HIP_MEMORY_SCOPE_AGENT);
    while (__hip_atomic_load(cnt, __ATOMIC_ACQUIRE, __HIP_MEMORY_SCOPE_AGENT) < target)
      __builtin_amdgcn_s_sleep(1);
    __threadfence();   // acquire
  }
  __syncthreads();
}

__global__ __launch_bounds__(512, 4) void k_fused(
    const float4* __restrict__ x4, const float* __restrict__ pm,
    const float* __restrict__ Wv, const float* __restrict__ bv,
    const float* __restrict__ gamma, const float* __restrict__ beta,
    const float* __restrict__ Wout, const float* __restrict__ bout,
    float* __restrict__ ws, float4* __restrict__ out4) {
  unsigned* cnt   = (unsigned*)ws;
  float*    part  = ws + 4;                 // NB*DD
  float*    vpart = part + NB * DD;         // 128*DD
  float*    zpart = vpart + 128 * DD;       // 128*DD

  const int tid = threadIdx.x;
  const int blk = blockIdx.x;

  __shared__ float4 sh4[512];     // phase 1 reduce
  __shared__ float  aSh[16];      // phase 2 cbar chunk
  __shared__ float  ySh[DD];      // phase 3 LN output
  __shared__ float  w1[8], w2[8]; // LN partial sums
  __shared__ float  zSh[BB * DD]; // phase 4 final z per batch

  // ---------------- Phase 1: column-sum partials of x -----------------------
  {
    const int bb    = blk >> 7;     // batch
    const int chunk = blk & 127;    // 64-row chunk
    const float4* p = x4 + ((size_t)bb * SS + (size_t)chunk * 64) * (DD / 4);
    float ax = 0.f, ay = 0.f, az = 0.f, aw = 0.f;
#pragma unroll
    for (int i = 0; i < 16; ++i) {  // 16*512 float4 = 64 rows
      float4 t = p[i * 512 + tid];
      ax += t.x; ay += t.y; az += t.z; aw += t.w;
    }
    sh4[tid] = make_float4(ax, ay, az, aw);
    __syncthreads();
    if (tid < 128) {
      float4 a0 = sh4[tid], a1 = sh4[tid + 128], a2 = sh4[tid + 256], a3 = sh4[tid + 384];
      float* dst = part + blk * DD + tid * 4;
      STORE_A(dst + 0, a0.x + a1.x + a2.x + a3.x);
      STORE_A(dst + 1, a0.y + a1.y + a2.y + a3.y);
      STORE_A(dst + 2, a0.z + a1.z + a2.z + a3.z);
      STORE_A(dst + 3, a0.w + a1.w + a2.w + a3.w);
    }
  }
  gbar(cnt, NB);

  // ---------------- Phase 2: vpart[bb,ch,j] = cbar_chunk @ Wv_chunk ---------
  if (blk < 128) {
    const int bb  = blk >> 5;
    const int ch  = blk & 31;
    const int d16 = tid >> 5;       // which of 16 columns in this chunk
    const int lane = tid & 31;
    const int col = ch * 16 + d16;
    float s = 0.f;
#pragma unroll
    for (int k = 0; k < 4; ++k)     // 128 x-partials of this batch
      s += LOAD_A(&part[(size_t)(bb * 128 + lane + 32 * k) * DD + col]);
    s += pm[lane * DD + col];       // 32 persistent tokens, one per lane
#pragma unroll
    for (int off = 16; off > 0; off >>= 1) s += __shfl_down(s, off, 32);
    if (lane == 0) aSh[d16] = s * (1.0f / (float)TT);
    __syncthreads();
    float acc = 0.f;
#pragma unroll
    for (int i = 0; i < 16; ++i)
      acc += aSh[i] * Wv[(ch * 16 + i) * DD + tid];
    STORE_A(&vpart[(bb * 32 + ch) * DD + tid], acc);
  }
  gbar(cnt, 2 * NB);

  // ---------------- Phase 3: LN(vbar) then zpart = y_chunk @ Wout_chunk -----
  if (blk < 128) {
    const int bb = blk >> 5;
    const int ch = blk & 31;
    float v = bv[tid];
#pragma unroll
    for (int c = 0; c < 32; ++c) v += LOAD_A(&vpart[(bb * 32 + c) * DD + tid]);

    float v1 = v, v2 = v * v;
#pragma unroll
    for (int off = 32; off > 0; off >>= 1) {
      v1 += __shfl_down(v1, off, 64);
      v2 += __shfl_down(v2, off, 64);
    }
    const int wave = tid >> 6;
    if ((tid & 63) == 0) { w1[wave] = v1; w2[wave] = v2; }
    __syncthreads();
    float t1 = 0.f, t2 = 0.f;
#pragma unroll
    for (int w = 0; w < 8; ++w) { t1 += w1[w]; t2 += w2[w]; }
    const float mu  = t1 * (1.0f / (float)DD);
    const float var = t2 * (1.0f / (float)DD) - mu * mu;
    const float inv = 1.0f / sqrtf(var + EPSV);
    ySh[tid] = (v - mu) * inv * gamma[tid] + beta[tid];
    __syncthreads();

    float acc = 0.f;
#pragma unroll
    for (int i = 0; i < 16; ++i)
      acc += ySh[ch * 16 + i] * Wout[(ch * 16 + i) * DD + tid];
    STORE_A(&zpart[(bb * 32 + ch) * DD + tid], acc);
  }
  gbar(cnt, 3 * NB);

  // ---------------- Phase 4: reduce z per batch, broadcast to out -----------
  {
#pragma unroll
    for (int bb = 0; bb < BB; ++bb) {
      float acc = bout[tid];
#pragma unroll 8
      for (int c = 0; c < 32; ++c)
        acc += LOAD_A(&zpart[(bb * 32 + c) * DD + tid]);
      zSh[bb * DD + tid] = acc;
    }
    __syncthreads();
    const float4* z4 = (const float4*)zSh;
    const unsigned total4 = (unsigned)BB * TT * DD / 4;     // 4,210,688
    for (unsigned i = blk * 512u + tid; i < total4; i += NB * 512u) {
      const unsigned bb = i / 1052672u;                     // T*D/4 per batch
      const unsigned j4 = i & 127u;                         // D/4 = 128
      out4[i] = z4[bb * 128u + j4];
    }
  }
}

// ---------------------------------------------------------------------------
extern "C" void kernel_launch(void* const* d_in, const int* in_sizes, int n_in,
                              void* d_out, int out_size, void* d_ws, size_t ws_size,
                              hipStream_t stream) {
  // setup_inputs() order:
  // 0:x 1:persistent_memory 2:Wk 3:bk 4:Wv 5:bv 6:Wq 7:bq 8:gamma 9:beta
  // 10:Wout 11:bout      (Wk/bk/Wq/bq are mathematically dead — see round 1)
  const float* x     = (const float*)d_in[0];
  const float* pm    = (const float*)d_in[1];
  const float* Wv    = (const float*)d_in[4];
  const float* bv    = (const float*)d_in[5];
  const float* gamma = (const float*)d_in[8];
  const float* beta  = (const float*)d_in[9];
  const float* Wout  = (const float*)d_in[10];
  const float* bout  = (const float*)d_in[11];

  // barrier counter must start at 0 (ws is re-poisoned to 0xAA every call)
  hipMemsetAsync(d_ws, 0, 16, stream);

  k_fused<<<NB, 512, 0, stream>>>((const float4*)x, pm, Wv, bv, gamma, beta,
                                  Wout, bout, (float*)d_ws, (float4*)d_out);
}

// Round 4
// 141.914 us; speedup vs baseline: 2.6579x; 2.6579x over previous
//
#include <hip/hip_runtime.h>
#include <math.h>

// Problem constants (B,S,D,P,M from the reference)
#define BB 4
#define SS 8192
#define DD 512
#define PP 32
#define TT (PP + SS)            // 8224 tokens after concat
#define EPSV 1e-5f

// Algebraic collapse (round 1): state0=0 => write-attn uniform => state rows
// identical => read-attn uniform => mem_out[b,t,:] = vbar[b,:] = cbar@Wv+bv
// where cbar = mean over T of concat(pm,x). Output = (LN(vbar)*g+b)@Wout+bout
// broadcast over all t. Wk/bk/Wq/bq are mathematically dead.
//
// Round 3 lesson: atomic-counter grid barrier costs ~77us/barrier on MI355X
// (cross-XCD invalidation storm). Kernel-boundary sync (~3us) is cheaper.
//
// ws layout (floats), all plain-store partials (no memset needed):
//   part [1024*DD]  colsum partials, 2 MB
//   vpart[128*DD]   split-K partials of cbar@Wv, 256 KB
//   z    [BB*DD]    final projection accum (zero-init by k_vbar, atomicAdd by k_zmat)

// ---------------------------------------------------------------------------
// Stage 1: part[blk, :] = column-sum of a 32-row chunk of x.
// 1024 blocks x 512 threads = 8192 waves = full 32-waves/CU oversubscription.
// 8 independent float4 loads in flight per thread.
// ---------------------------------------------------------------------------
__global__ __launch_bounds__(512) void k_colsum(const float4* __restrict__ x4,
                                                float4* __restrict__ part4) {
  const int bb    = blockIdx.x >> 8;    // batch (256 chunks per batch)
  const int chunk = blockIdx.x & 255;   // 32-row chunk
  const int tid   = threadIdx.x;

  const float4* p = x4 + ((size_t)bb * SS + (size_t)chunk * 32) * (DD / 4);

  float ax = 0.f, ay = 0.f, az = 0.f, aw = 0.f;
#pragma unroll
  for (int i = 0; i < 8; ++i) {         // 8*512 float4 = 32 rows
    float4 t = p[i * 512 + tid];
    ax += t.x; ay += t.y; az += t.z; aw += t.w;
  }

  __shared__ float4 sh[512];
  sh[tid] = make_float4(ax, ay, az, aw);
  __syncthreads();

  // threads tid, tid+128, tid+256, tid+384 share column-group tid&127
  if (tid < 128) {
    float4 a0 = sh[tid], a1 = sh[tid + 128], a2 = sh[tid + 256], a3 = sh[tid + 384];
    part4[blockIdx.x * 128 + tid] =
        make_float4(a0.x + a1.x + a2.x + a3.x, a0.y + a1.y + a2.y + a3.y,
                    a0.z + a1.z + a2.z + a3.z, a0.w + a1.w + a2.w + a3.w);
  }
}

// ---------------------------------------------------------------------------
// Stage 2: vpart[bb,ch,j] = cbar[16-chunk] @ Wv[16-chunk, j], plain store.
// Grid: BB*32 = 128 blocks, 512 threads. cbar chunk computed by reducing the
// 256 colsum partials of this batch + the 32 persistent-memory rows.
// Blocks 0..3 also zero-init z for stage 3's atomicAdd.
// ---------------------------------------------------------------------------
__global__ __launch_bounds__(512) void k_vbar(const float* __restrict__ part,
                                              const float* __restrict__ pm,
                                              const float* __restrict__ Wv,
                                              float* __restrict__ vpart,
                                              float* __restrict__ z) {
  const int bb = blockIdx.x >> 5;       // batch
  const int ch = blockIdx.x & 31;       // 16-column chunk of cbar
  const int j  = threadIdx.x;

  __shared__ float aSh[16];
  {
    const int d16  = j >> 5;            // 16 groups of 32 lanes
    const int lane = j & 31;
    const int col  = ch * 16 + d16;
    float s = 0.f;
#pragma unroll
    for (int k = 0; k < 8; ++k)         // 256 partial rows of this batch
      s += part[(size_t)(bb * 256 + lane + 32 * k) * DD + col];
    s += pm[lane * DD + col];           // 32 persistent tokens, one per lane
#pragma unroll
    for (int off = 16; off > 0; off >>= 1) s += __shfl_down(s, off, 32);
    if (lane == 0) aSh[d16] = s * (1.0f / (float)TT);
  }
  __syncthreads();

  float acc = 0.f;
#pragma unroll
  for (int i = 0; i < 16; ++i)
    acc += aSh[i] * Wv[(ch * 16 + i) * DD + j];
  vpart[(bb * 32 + ch) * DD + j] = acc;

  if (blockIdx.x < BB) z[blockIdx.x * DD + j] = 0.f;   // init for stage 3
}

// ---------------------------------------------------------------------------
// Stage 3: vbar = bv + sum of vpart chunks; LN stats (redundant per block);
// z[b,j] += y[16-chunk] @ Wout[16-chunk, j]. Grid: 128 blocks, 512 threads.
// ---------------------------------------------------------------------------
__global__ __launch_bounds__(512) void k_zmat(const float* __restrict__ vpart,
                                              const float* __restrict__ bv,
                                              const float* __restrict__ gamma,
                                              const float* __restrict__ beta,
                                              const float* __restrict__ Wout,
                                              float* __restrict__ z) {
  const int bb = blockIdx.x >> 5;
  const int ch = blockIdx.x & 31;
  const int j  = threadIdx.x;

  float v = bv[j];
#pragma unroll
  for (int c = 0; c < 32; ++c) v += vpart[(bb * 32 + c) * DD + j];

  // block mean/var across 512 threads
  float v1 = v, v2 = v * v;
#pragma unroll
  for (int off = 32; off > 0; off >>= 1) {
    v1 += __shfl_down(v1, off, 64);
    v2 += __shfl_down(v2, off, 64);
  }
  __shared__ float w1[8], w2[8];
  const int wave = j >> 6;
  if ((j & 63) == 0) { w1[wave] = v1; w2[wave] = v2; }
  __syncthreads();
  float t1 = 0.f, t2 = 0.f;
#pragma unroll
  for (int w = 0; w < 8; ++w) { t1 += w1[w]; t2 += w2[w]; }
  const float mu  = t1 * (1.0f / (float)DD);
  const float var = t2 * (1.0f / (float)DD) - mu * mu;
  const float inv = 1.0f / sqrtf(var + EPSV);

  __shared__ float y[DD];
  y[j] = (v - mu) * inv * gamma[j] + beta[j];
  __syncthreads();

  float acc = 0.f;
#pragma unroll
  for (int i = 0; i < 16; ++i)
    acc += y[ch * 16 + i] * Wout[(ch * 16 + i) * DD + j];
  atomicAdd(&z[bb * DD + j], acc);
}

// ---------------------------------------------------------------------------
// Stage 4: out[b,t,:] = z[b,:] + bout, broadcast over all t. float4 stores.
// ---------------------------------------------------------------------------
__global__ __launch_bounds__(256) void k_bcast(const float4* __restrict__ z4,
                                               const float4* __restrict__ bout4,
                                               float4* __restrict__ out4) {
  const unsigned i  = blockIdx.x * 256u + threadIdx.x;     // float4 index
  const unsigned bb = i / 1052672u;                        // T*D/4 per batch
  const unsigned j4 = i & 127u;                            // column group (D/4=128)
  float4 zz = z4[bb * 128u + j4];
  float4 bo = bout4[j4];
  out4[i] = make_float4(zz.x + bo.x, zz.y + bo.y, zz.z + bo.z, zz.w + bo.w);
}

// ---------------------------------------------------------------------------
extern "C" void kernel_launch(void* const* d_in, const int* in_sizes, int n_in,
                              void* d_out, int out_size, void* d_ws, size_t ws_size,
                              hipStream_t stream) {
  // setup_inputs() order:
  // 0:x 1:persistent_memory 2:Wk 3:bk 4:Wv 5:bv 6:Wq 7:bq 8:gamma 9:beta
  // 10:Wout 11:bout      (Wk/bk/Wq/bq mathematically dead — see round 1)
  const float* x     = (const float*)d_in[0];
  const float* pm    = (const float*)d_in[1];
  const float* Wv    = (const float*)d_in[4];
  const float* bv    = (const float*)d_in[5];
  const float* gamma = (const float*)d_in[8];
  const float* beta  = (const float*)d_in[9];
  const float* Wout  = (const float*)d_in[10];
  const float* bout  = (const float*)d_in[11];

  float* part  = (float*)d_ws;            // 1024*DD floats (2 MB)
  float* vpart = part + 1024 * DD;        // 128*DD floats (256 KB)
  float* z     = vpart + 128 * DD;        // BB*DD floats (8 KB)

  k_colsum<<<1024, 512, 0, stream>>>((const float4*)x, (float4*)part);

  k_vbar<<<BB * 32, 512, 0, stream>>>(part, pm, Wv, vpart, z);

  k_zmat<<<BB * 32, 512, 0, stream>>>(vpart, bv, gamma, beta, Wout, z);

  const unsigned total4 = (unsigned)BB * TT * DD / 4;      // 4,210,688
  k_bcast<<<total4 / 256, 256, 0, stream>>>((const float4*)z,
                                            (const float4*)bout,
                                            (float4*)d_out);
}